// Round 1
// baseline (376.925 us; speedup 1.0000x reference)
//
#include <hip/hip_runtime.h>
#include <hip/hip_bf16.h>
#include <math.h>

// ---------------------------------------------------------------------------
// SplineCNN-style net on MI355X.
// Pipeline:
//   L1: spline_conv(x 200704x1 -> 32) + ELU        [dedicated gather kernel]
//   P1: voxel max-pool 28x28 -> 6x6 (9216 cells)   [analytic gather]
//   L2: spline_conv(32->64) via U-matrix + GEMM    [U build + GEMM(9216x832x64)]
//   P2: pool 6x6 -> 4x4 (4096 cells)               [generic gather]
//   L3: spline_conv(64->64)                        [U build + GEMM(4096x1664x64)]
//   P3: pool 4x4 -> 2x2 (1024 cells)
//   FC1 GEMM(256x256x128)+ELU, FC2+log_softmax
// All fp32. 1/cnt folded into U; x@root folded as extra K-columns of the GEMM.
// ---------------------------------------------------------------------------

#define DEV __device__ __forceinline__

DEV float elu_f(float v) { return v > 0.f ? v : expm1f(v); }

DEV void corners(float p0, float p1,
                 int& k00, int& k01, int& k10, int& k11,
                 float& w00, float& w01, float& w10, float& w11) {
  // v = clip(p,0,1)*(K-1); i0=clip(floor(v),0,K-1); frac=v-i0; i1=min(i0+1,K-1)
  float v0 = fminf(fmaxf(p0, 0.f), 1.f) * 4.f;
  float v1 = fminf(fmaxf(p1, 0.f), 1.f) * 4.f;
  int i0 = (int)v0; i0 = i0 > 4 ? 4 : i0;
  int j0 = (int)v1; j0 = j0 > 4 ? 4 : j0;
  float f0 = v0 - (float)i0;
  float f1 = v1 - (float)j0;
  int i1 = i0 + 1 > 4 ? 4 : i0 + 1;
  int j1 = j0 + 1 > 4 ? 4 : j0 + 1;
  k00 = i0 * 5 + j0; k01 = i0 * 5 + j1; k10 = i1 * 5 + j0; k11 = i1 * 5 + j1;
  w00 = (1.f - f0) * (1.f - f1); w01 = (1.f - f0) * f1;
  w10 = f0 * (1.f - f1);         w11 = f0 * f1;
}

// --------------------------- Layer 1 (F=1 -> 32) ---------------------------
// One thread per node. Edge id reconstructed from grid_edges_np ordering.
__global__ __launch_bounds__(256) void spline1_kernel(
    const float* __restrict__ xin, const float* __restrict__ pseudo,
    const float* __restrict__ W1, const float* __restrict__ root1,
    const float* __restrict__ b1, float* __restrict__ out1) {
  __shared__ float Wl[800];  // 25 x 32
  int t = threadIdx.x;
  for (int i = t; i < 800; i += 256) Wl[i] = W1[i];
  __syncthreads();

  int n = blockIdx.x * 256 + t;  // exactly 200704 threads
  int b = n / 784, r = n % 784, y = r / 28, x = r % 28;

  float acc[32];
#pragma unroll
  for (int g = 0; g < 32; g++) acc[g] = 0.f;

  const int dys[8] = {-1, -1, -1, 0, 0, 1, 1, 1};
  const int dxs[8] = {-1, 0, 1, -1, 1, -1, 0, 1};
  int off = 0;
#pragma unroll
  for (int d = 0; d < 8; d++) {
    int dy = dys[d], dx = dxs[d];
    int ady = dy < 0 ? -dy : dy, adx = dx < 0 ? -dx : dx;
    int bh = 28 - ady, bw = 28 - adx;
    int sy = y - dy, sx = x - dx;
    if (sy >= 0 && sy < 28 && sx >= 0 && sx < 28) {
      int local = (y - (dy > 0 ? dy : 0)) * bw + (x - (dx > 0 ? dx : 0));
      int eid = b * 5940 + off + local;
      float p0 = pseudo[2 * eid], p1 = pseudo[2 * eid + 1];
      int k00, k01, k10, k11; float w00, w01, w10, w11;
      corners(p0, p1, k00, k01, k10, k11, w00, w01, w10, w11);
      float xs = xin[b * 784 + sy * 28 + sx];
      const float* r00 = &Wl[k00 * 32];
      const float* r01 = &Wl[k01 * 32];
      const float* r10 = &Wl[k10 * 32];
      const float* r11 = &Wl[k11 * 32];
#pragma unroll
      for (int q = 0; q < 8; q++) {
        float4 a0 = *(const float4*)&r00[q * 4];
        float4 a1 = *(const float4*)&r01[q * 4];
        float4 a2 = *(const float4*)&r10[q * 4];
        float4 a3 = *(const float4*)&r11[q * 4];
        acc[q * 4 + 0] += xs * (w00 * a0.x + w01 * a1.x + w10 * a2.x + w11 * a3.x);
        acc[q * 4 + 1] += xs * (w00 * a0.y + w01 * a1.y + w10 * a2.y + w11 * a3.y);
        acc[q * 4 + 2] += xs * (w00 * a0.z + w01 * a1.z + w10 * a2.z + w11 * a3.z);
        acc[q * 4 + 3] += xs * (w00 * a0.w + w01 * a1.w + w10 * a2.w + w11 * a3.w);
      }
    }
    off += bh * bw;
  }
  float cnt = (float)((1 + (y > 0) + (y < 27)) * (1 + (x > 0) + (x < 27)) - 1);
  float inv = 1.f / cnt;
  float xv = xin[n];
#pragma unroll
  for (int g = 0; g < 32; g++) {
    float v = acc[g] * inv + xv * root1[g] + b1[g];
    out1[n * 32 + g] = elu_f(v);
  }
}

// --------------------------- Pool 1 (analytic) -----------------------------
__global__ __launch_bounds__(256) void pool1_kernel(
    const float* __restrict__ h1, const float* __restrict__ pos,
    float* __restrict__ h1p, float* __restrict__ pos1) {
  int id = blockIdx.x * 256 + threadIdx.x;  // 9216*32 threads
  int g = id % 32, s = id / 32;
  int b = s / 36, r = s % 36, cy = r / 6, cx = r % 6;
  int y0 = cy * 5, y1 = y0 + 5 > 28 ? 28 : y0 + 5;
  int x0 = cx * 5, x1 = x0 + 5 > 28 ? 28 : x0 + 5;
  float vmax = -3.4e38f;
  float psum = 0.f;
  for (int y = y0; y < y1; y++)
    for (int x = x0; x < x1; x++) {
      int nn = b * 784 + y * 28 + x;
      vmax = fmaxf(vmax, h1[nn * 32 + g]);
      if (g < 2) psum += pos[nn * 2 + g];
    }
  h1p[s * 32 + g] = vmax;
  if (g < 2) pos1[s * 2 + g] = psum / (float)((y1 - y0) * (x1 - x0));
}

// ---------------- global max|cart| over grid edges (atomicMax) -------------
__global__ __launch_bounds__(256) void maxcart_kernel(
    const float* __restrict__ posl, unsigned* __restrict__ outmax,
    int gh, int gw, int total) {
  int s = blockIdx.x * 256 + threadIdx.x;
  if (s >= total) return;
  int per = gh * gw;
  int b = s / per, r = s % per, cy = r / gw, cx = r % gw;
  const int dys[8] = {-1, -1, -1, 0, 0, 1, 1, 1};
  const int dxs[8] = {-1, 0, 1, -1, 1, -1, 0, 1};
  float px = posl[s * 2], py = posl[s * 2 + 1];
  float m = 0.f;
#pragma unroll
  for (int d = 0; d < 8; d++) {
    int sy = cy - dys[d], sx = cx - dxs[d];
    if (sy >= 0 && sy < gh && sx >= 0 && sx < gw) {
      int src = b * per + sy * gw + sx;
      m = fmaxf(m, fabsf(px - posl[src * 2]));
      m = fmaxf(m, fabsf(py - posl[src * 2 + 1]));
    }
  }
  atomicMax(outmax, __float_as_uint(m));  // floats >= 0: bit order == value order
}

// ------------------- U-matrix build (layers 2 & 3) -------------------------
// Thread (dst,f). A row layout: [k0 f0..fF-1 | k1 ... | k24 ... | root cols].
__global__ __launch_bounds__(128) void ubuild_kernel(
    const float* __restrict__ xl, const float* __restrict__ posl,
    const unsigned* __restrict__ maxc, float* __restrict__ Aout,
    int F, int gh, int gw) {
  __shared__ float accs[128 * 25];
  int t = threadIdx.x;
  float* acc = &accs[t * 25];
  int id = blockIdx.x * 128 + t;  // total = cells*F, exact multiple of 128
  int f = id % F, dst = id / F;
  int per = gh * gw;
  int b = dst / per, r = dst % per, cy = r / gw, cx = r % gw;
#pragma unroll
  for (int k = 0; k < 25; k++) acc[k] = 0.f;
  float M = __uint_as_float(*maxc);
  float inv2M = 0.5f / M;
  int cnt = (1 + (cy > 0) + (cy < gh - 1)) * (1 + (cx > 0) + (cx < gw - 1)) - 1;
  float invc = 1.f / (float)cnt;
  float pdx = posl[dst * 2], pdy = posl[dst * 2 + 1];
  const int dys[8] = {-1, -1, -1, 0, 0, 1, 1, 1};
  const int dxs[8] = {-1, 0, 1, -1, 1, -1, 0, 1};
#pragma unroll
  for (int d = 0; d < 8; d++) {
    int sy = cy - dys[d], sx = cx - dxs[d];
    if (sy >= 0 && sy < gh && sx >= 0 && sx < gw) {
      int src = b * per + sy * gw + sx;
      float cartx = pdx - posl[src * 2];
      float carty = pdy - posl[src * 2 + 1];
      float p0 = cartx * inv2M + 0.5f;
      float p1 = carty * inv2M + 0.5f;
      int k00, k01, k10, k11; float w00, w01, w10, w11;
      corners(p0, p1, k00, k01, k10, k11, w00, w01, w10, w11);
      float xs = xl[src * F + f] * invc;
      acc[k00] += w00 * xs;
      acc[k01] += w01 * xs;
      acc[k10] += w10 * xs;
      acc[k11] += w11 * xs;
    }
  }
  int ldA = 26 * F;
  float* Ar = &Aout[(size_t)dst * ldA];
#pragma unroll
  for (int k = 0; k < 25; k++) Ar[k * F + f] = acc[k];
  Ar[25 * F + f] = xl[dst * F + f];  // root columns
}

// ------------------------ concat W_flat and root ---------------------------
__global__ __launch_bounds__(256) void concat_kernel(
    const float* __restrict__ A, int na, const float* __restrict__ Bp, int nb,
    float* __restrict__ outp) {
  int i = blockIdx.x * 256 + threadIdx.x;
  if (i < na) outp[i] = A[i];
  else if (i < na + nb) outp[i] = Bp[i - na];
}

// ------------------------------- GEMM --------------------------------------
// C[M,N] = A[M,K] @ B[K,N] + bias[N], optional ELU. M%64==0, N%64==0, K%16==0.
__global__ __launch_bounds__(256) void gemm_kernel(
    const float* __restrict__ A, const float* __restrict__ B,
    const float* __restrict__ bias, float* __restrict__ C,
    int M, int N, int K, int do_elu) {
  __shared__ float At[16][64];
  __shared__ float Bt[16][64];
  int n0 = blockIdx.x * 64, m0 = blockIdx.y * 64;
  int t = threadIdx.x;
  int tx = t % 16, ty = t / 16;
  int ar = t / 4, ak = (t % 4) * 4;
  int bk = t / 16, bn = (t % 16) * 4;
  float acc[4][4];
#pragma unroll
  for (int i = 0; i < 4; i++)
#pragma unroll
    for (int j = 0; j < 4; j++) acc[i][j] = 0.f;

  for (int k0 = 0; k0 < K; k0 += 16) {
    float4 av = *(const float4*)&A[(size_t)(m0 + ar) * K + k0 + ak];
    float4 bv = *(const float4*)&B[(size_t)(k0 + bk) * N + n0 + bn];
    __syncthreads();
    At[ak + 0][ar] = av.x; At[ak + 1][ar] = av.y;
    At[ak + 2][ar] = av.z; At[ak + 3][ar] = av.w;
    *(float4*)&Bt[bk][bn] = bv;
    __syncthreads();
#pragma unroll
    for (int kk = 0; kk < 16; kk++) {
      float4 a = *(const float4*)&At[kk][ty * 4];
      float4 bq = *(const float4*)&Bt[kk][tx * 4];
      acc[0][0] += a.x * bq.x; acc[0][1] += a.x * bq.y; acc[0][2] += a.x * bq.z; acc[0][3] += a.x * bq.w;
      acc[1][0] += a.y * bq.x; acc[1][1] += a.y * bq.y; acc[1][2] += a.y * bq.z; acc[1][3] += a.y * bq.w;
      acc[2][0] += a.z * bq.x; acc[2][1] += a.z * bq.y; acc[2][2] += a.z * bq.z; acc[2][3] += a.z * bq.w;
      acc[3][0] += a.w * bq.x; acc[3][1] += a.w * bq.y; acc[3][2] += a.w * bq.z; acc[3][3] += a.w * bq.w;
    }
  }
#pragma unroll
  for (int i = 0; i < 4; i++) {
    int m = m0 + ty * 4 + i;
#pragma unroll
    for (int j = 0; j < 4; j++) {
      int n = n0 + tx * 4 + j;
      float v = acc[i][j] + bias[n];
      if (do_elu) v = elu_f(v);
      C[(size_t)m * N + n] = v;
    }
  }
}

// -------------------- generic pool (pools 2 & 3) ---------------------------
__global__ __launch_bounds__(256) void poolgen_kernel(
    const float* __restrict__ xl, const float* __restrict__ posl,
    float* __restrict__ xout, float* __restrict__ posout,
    int F, int perin, int gOut, float size) {
  int id = blockIdx.x * 256 + threadIdx.x;  // B*gOut*gOut*F threads exact
  int g = id % F, s = id / F;
  int per = gOut * gOut;
  int b = s / per, r = s % per;
  float vmax = -3.4e38f;
  float psum = 0.f;
  int cnt = 0;
  for (int j = 0; j < perin; j++) {
    int nc = b * perin + j;
    float px = posl[nc * 2], py = posl[nc * 2 + 1];
    int c2x = (int)floorf(px / size); c2x = c2x < 0 ? 0 : (c2x > gOut - 1 ? gOut - 1 : c2x);
    int c2y = (int)floorf(py / size); c2y = c2y < 0 ? 0 : (c2y > gOut - 1 ? gOut - 1 : c2y);
    if (c2y * gOut + c2x == r) {
      vmax = fmaxf(vmax, xl[nc * F + g]);
      cnt++;
      if (g < 2) psum += posl[nc * 2 + g];
    }
  }
  xout[s * F + g] = vmax;
  if (g < 2 && posout) posout[s * 2 + g] = psum / (float)cnt;
}

// --------------------- FC2 + log_softmax (256 rows) ------------------------
__global__ __launch_bounds__(256) void fc2_lsm_kernel(
    const float* __restrict__ h4, const float* __restrict__ w,
    const float* __restrict__ bias, float* __restrict__ out) {
  int row = threadIdx.x;  // one block of 256
  float l[10];
#pragma unroll
  for (int j = 0; j < 10; j++) l[j] = bias[j];
  for (int k = 0; k < 128; k++) {
    float hv = h4[row * 128 + k];
#pragma unroll
    for (int j = 0; j < 10; j++) l[j] += hv * w[k * 10 + j];
  }
  float m = l[0];
#pragma unroll
  for (int j = 1; j < 10; j++) m = fmaxf(m, l[j]);
  float ssum = 0.f;
#pragma unroll
  for (int j = 0; j < 10; j++) ssum += expf(l[j] - m);
  float lse = logf(ssum);
#pragma unroll
  for (int j = 0; j < 10; j++) out[row * 10 + j] = l[j] - m - lse;
}

// ---------------------------------------------------------------------------
extern "C" void kernel_launch(void* const* d_in, const int* in_sizes, int n_in,
                              void* d_out, int out_size, void* d_ws, size_t ws_size,
                              hipStream_t stream) {
  const float* x      = (const float*)d_in[0];
  const float* pos    = (const float*)d_in[1];
  const float* pseudo = (const float*)d_in[2];
  const float* W1     = (const float*)d_in[3];
  const float* root1  = (const float*)d_in[4];
  const float* b1     = (const float*)d_in[5];
  const float* W2     = (const float*)d_in[6];
  const float* root2  = (const float*)d_in[7];
  const float* b2     = (const float*)d_in[8];
  const float* W3     = (const float*)d_in[9];
  const float* root3  = (const float*)d_in[10];
  const float* b3     = (const float*)d_in[11];
  const float* fc1w   = (const float*)d_in[12];
  const float* fc1b   = (const float*)d_in[13];
  const float* fc2w   = (const float*)d_in[14];
  const float* fc2b   = (const float*)d_in[15];
  float* out = (float*)d_out;

  // workspace layout (floats)
  float* ws = (float*)d_ws;
  size_t o = 0;
  float* w_out1 = ws + o; o += (size_t)200704 * 32;   // 6422528
  float* w_h1p  = ws + o; o += (size_t)9216 * 32;
  float* w_pos1 = ws + o; o += (size_t)9216 * 2;
  float* w_A    = ws + o; o += (size_t)9216 * 832;    // shared by A2 (9216x832) and A3 (4096x1664)
  float* w_B2   = ws + o; o += (size_t)832 * 64;
  float* w_B3   = ws + o; o += (size_t)1664 * 64;
  float* w_h2   = ws + o; o += (size_t)9216 * 64;
  float* w_pos2 = ws + o; o += (size_t)4096 * 2;
  float* w_h2p  = ws + o; o += (size_t)4096 * 64;
  float* w_h3   = ws + o; o += (size_t)4096 * 64;
  float* w_h3p  = ws + o; o += (size_t)1024 * 64;
  float* w_h4   = ws + o; o += (size_t)256 * 128;
  unsigned* w_maxc2 = (unsigned*)(ws + o); o += 4;
  unsigned* w_maxc3 = (unsigned*)(ws + o); o += 4;

  // zero the two atomicMax scalars
  hipMemsetAsync(w_maxc2, 0, 4, stream);
  hipMemsetAsync(w_maxc3, 0, 4, stream);

  // L1: spline conv 1->32 + ELU
  spline1_kernel<<<784, 256, 0, stream>>>(x, pseudo, W1, root1, b1, w_out1);
  // P1: pool to 6x6
  pool1_kernel<<<1152, 256, 0, stream>>>(w_out1, pos, w_h1p, w_pos1);
  // L2
  maxcart_kernel<<<36, 256, 0, stream>>>(w_pos1, w_maxc2, 6, 6, 9216);
  ubuild_kernel<<<2304, 128, 0, stream>>>(w_h1p, w_pos1, w_maxc2, w_A, 32, 6, 6);
  concat_kernel<<<208, 256, 0, stream>>>(W2, 25 * 32 * 64, root2, 32 * 64, w_B2);
  gemm_kernel<<<dim3(1, 144), 256, 0, stream>>>(w_A, w_B2, b2, w_h2, 9216, 64, 832, 1);
  // P2: pool to 4x4
  poolgen_kernel<<<1024, 256, 0, stream>>>(w_h2, w_pos1, w_h2p, w_pos2, 64, 36, 4, 7.0f);
  // L3
  maxcart_kernel<<<16, 256, 0, stream>>>(w_pos2, w_maxc3, 4, 4, 4096);
  ubuild_kernel<<<2048, 128, 0, stream>>>(w_h2p, w_pos2, w_maxc3, w_A, 64, 4, 4);
  concat_kernel<<<416, 256, 0, stream>>>(W3, 25 * 64 * 64, root3, 64 * 64, w_B3);
  gemm_kernel<<<dim3(1, 64), 256, 0, stream>>>(w_A, w_B3, b3, w_h3, 4096, 64, 1664, 1);
  // P3: pool to 2x2 (pos output unused)
  poolgen_kernel<<<256, 256, 0, stream>>>(w_h3, w_pos2, w_h3p, nullptr, 64, 16, 2, 14.0f);
  // FC1: (256x256)@(256x128)+b, ELU   (h3p memory == reshape(B, 256))
  gemm_kernel<<<dim3(2, 4), 256, 0, stream>>>(w_h3p, fc1w, fc1b, w_h4, 256, 128, 256, 1);
  // FC2 + log_softmax
  fc2_lsm_kernel<<<1, 256, 0, stream>>>(w_h4, fc2w, fc2b, out);
}

// Round 2
// 281.637 us; speedup vs baseline: 1.3383x; 1.3383x over previous
//
#include <hip/hip_runtime.h>
#include <hip/hip_bf16.h>
#include <math.h>

// ---------------------------------------------------------------------------
// SplineCNN-style net on MI355X.
//   L1: spline_conv(1->32)+ELU [gather]  P1: 28x28->6x6
//   L2: U-build + split-K GEMM(9216x832x64) + reduce(bias,ELU)   P2: 6x6->4x4
//   L3: U-build + split-K GEMM(4096x1664x64) + reduce            P3: 4x4->2x2
//   FC1 GEMM(256x256x128)+ELU, FC2+log_softmax
// Round 1 -> 2: GEMMs were 88us each at 2.7% occupancy (144 / 64 blocks on
// 256 CUs, latency-bound). Split-K (chunk=208: 832=4*208, 1664=8*208) gives
// 576 / 512 blocks + tiny reduce kernel. Pack/memset fused into one kernel.
// ---------------------------------------------------------------------------

#define DEV __device__ __forceinline__

DEV float elu_f(float v) { return v > 0.f ? v : expm1f(v); }

DEV void corners(float p0, float p1,
                 int& k00, int& k01, int& k10, int& k11,
                 float& w00, float& w01, float& w10, float& w11) {
  float v0 = fminf(fmaxf(p0, 0.f), 1.f) * 4.f;
  float v1 = fminf(fmaxf(p1, 0.f), 1.f) * 4.f;
  int i0 = (int)v0; i0 = i0 > 4 ? 4 : i0;
  int j0 = (int)v1; j0 = j0 > 4 ? 4 : j0;
  float f0 = v0 - (float)i0;
  float f1 = v1 - (float)j0;
  int i1 = i0 + 1 > 4 ? 4 : i0 + 1;
  int j1 = j0 + 1 > 4 ? 4 : j0 + 1;
  k00 = i0 * 5 + j0; k01 = i0 * 5 + j1; k10 = i1 * 5 + j0; k11 = i1 * 5 + j1;
  w00 = (1.f - f0) * (1.f - f1); w01 = (1.f - f0) * f1;
  w10 = f0 * (1.f - f1);         w11 = f0 * f1;
}

// --------------------------- Layer 1 (F=1 -> 32) ---------------------------
__global__ __launch_bounds__(256) void spline1_kernel(
    const float* __restrict__ xin, const float* __restrict__ pseudo,
    const float* __restrict__ W1, const float* __restrict__ root1,
    const float* __restrict__ b1, float* __restrict__ out1) {
  __shared__ float Wl[800];  // 25 x 32
  int t = threadIdx.x;
  for (int i = t; i < 800; i += 256) Wl[i] = W1[i];
  __syncthreads();

  int n = blockIdx.x * 256 + t;  // exactly 200704 threads
  int b = n / 784, r = n % 784, y = r / 28, x = r % 28;

  float acc[32];
#pragma unroll
  for (int g = 0; g < 32; g++) acc[g] = 0.f;

  const int dys[8] = {-1, -1, -1, 0, 0, 1, 1, 1};
  const int dxs[8] = {-1, 0, 1, -1, 1, -1, 0, 1};
  int off = 0;
#pragma unroll
  for (int d = 0; d < 8; d++) {
    int dy = dys[d], dx = dxs[d];
    int ady = dy < 0 ? -dy : dy, adx = dx < 0 ? -dx : dx;
    int bh = 28 - ady, bw = 28 - adx;
    int sy = y - dy, sx = x - dx;
    if (sy >= 0 && sy < 28 && sx >= 0 && sx < 28) {
      int local = (y - (dy > 0 ? dy : 0)) * bw + (x - (dx > 0 ? dx : 0));
      int eid = b * 5940 + off + local;
      float p0 = pseudo[2 * eid], p1 = pseudo[2 * eid + 1];
      int k00, k01, k10, k11; float w00, w01, w10, w11;
      corners(p0, p1, k00, k01, k10, k11, w00, w01, w10, w11);
      float xs = xin[b * 784 + sy * 28 + sx];
      const float* r00 = &Wl[k00 * 32];
      const float* r01 = &Wl[k01 * 32];
      const float* r10 = &Wl[k10 * 32];
      const float* r11 = &Wl[k11 * 32];
#pragma unroll
      for (int q = 0; q < 8; q++) {
        float4 a0 = *(const float4*)&r00[q * 4];
        float4 a1 = *(const float4*)&r01[q * 4];
        float4 a2 = *(const float4*)&r10[q * 4];
        float4 a3 = *(const float4*)&r11[q * 4];
        acc[q * 4 + 0] += xs * (w00 * a0.x + w01 * a1.x + w10 * a2.x + w11 * a3.x);
        acc[q * 4 + 1] += xs * (w00 * a0.y + w01 * a1.y + w10 * a2.y + w11 * a3.y);
        acc[q * 4 + 2] += xs * (w00 * a0.z + w01 * a1.z + w10 * a2.z + w11 * a3.z);
        acc[q * 4 + 3] += xs * (w00 * a0.w + w01 * a1.w + w10 * a2.w + w11 * a3.w);
      }
    }
    off += bh * bw;
  }
  float cnt = (float)((1 + (y > 0) + (y < 27)) * (1 + (x > 0) + (x < 27)) - 1);
  float inv = 1.f / cnt;
  float xv = xin[n];
#pragma unroll
  for (int g = 0; g < 32; g++) {
    float v = acc[g] * inv + xv * root1[g] + b1[g];
    out1[n * 32 + g] = elu_f(v);
  }
}

// --------------------------- Pool 1 (analytic) -----------------------------
__global__ __launch_bounds__(256) void pool1_kernel(
    const float* __restrict__ h1, const float* __restrict__ pos,
    float* __restrict__ h1p, float* __restrict__ pos1) {
  int id = blockIdx.x * 256 + threadIdx.x;  // 9216*32 threads
  int g = id % 32, s = id / 32;
  int b = s / 36, r = s % 36, cy = r / 6, cx = r % 6;
  int y0 = cy * 5, y1 = y0 + 5 > 28 ? 28 : y0 + 5;
  int x0 = cx * 5, x1 = x0 + 5 > 28 ? 28 : x0 + 5;
  float vmax = -3.4e38f;
  float psum = 0.f;
  for (int y = y0; y < y1; y++)
    for (int x = x0; x < x1; x++) {
      int nn = b * 784 + y * 28 + x;
      vmax = fmaxf(vmax, h1[nn * 32 + g]);
      if (g < 2) psum += pos[nn * 2 + g];
    }
  h1p[s * 32 + g] = vmax;
  if (g < 2) pos1[s * 2 + g] = psum / (float)((y1 - y0) * (x1 - x0));
}

// ---------------- global max|cart| over grid edges (atomicMax) -------------
__global__ __launch_bounds__(256) void maxcart_kernel(
    const float* __restrict__ posl, unsigned* __restrict__ outmax,
    int gh, int gw, int total) {
  int s = blockIdx.x * 256 + threadIdx.x;
  if (s >= total) return;
  int per = gh * gw;
  int b = s / per, r = s % per, cy = r / gw, cx = r % gw;
  const int dys[8] = {-1, -1, -1, 0, 0, 1, 1, 1};
  const int dxs[8] = {-1, 0, 1, -1, 1, -1, 0, 1};
  float px = posl[s * 2], py = posl[s * 2 + 1];
  float m = 0.f;
#pragma unroll
  for (int d = 0; d < 8; d++) {
    int sy = cy - dys[d], sx = cx - dxs[d];
    if (sy >= 0 && sy < gh && sx >= 0 && sx < gw) {
      int src = b * per + sy * gw + sx;
      m = fmaxf(m, fabsf(px - posl[src * 2]));
      m = fmaxf(m, fabsf(py - posl[src * 2 + 1]));
    }
  }
  atomicMax(outmax, __float_as_uint(m));  // floats >= 0: bit order == value order
}

// ------------------- U-matrix build (layers 2 & 3) -------------------------
__global__ __launch_bounds__(128) void ubuild_kernel(
    const float* __restrict__ xl, const float* __restrict__ posl,
    const unsigned* __restrict__ maxc, float* __restrict__ Aout,
    int F, int gh, int gw) {
  __shared__ float accs[128 * 25];
  int t = threadIdx.x;
  float* acc = &accs[t * 25];
  int id = blockIdx.x * 128 + t;  // total = cells*F, exact multiple of 128
  int f = id % F, dst = id / F;
  int per = gh * gw;
  int b = dst / per, r = dst % per, cy = r / gw, cx = r % gw;
#pragma unroll
  for (int k = 0; k < 25; k++) acc[k] = 0.f;
  float M = __uint_as_float(*maxc);
  float inv2M = 0.5f / M;
  int cnt = (1 + (cy > 0) + (cy < gh - 1)) * (1 + (cx > 0) + (cx < gw - 1)) - 1;
  float invc = 1.f / (float)cnt;
  float pdx = posl[dst * 2], pdy = posl[dst * 2 + 1];
  const int dys[8] = {-1, -1, -1, 0, 0, 1, 1, 1};
  const int dxs[8] = {-1, 0, 1, -1, 1, -1, 0, 1};
#pragma unroll
  for (int d = 0; d < 8; d++) {
    int sy = cy - dys[d], sx = cx - dxs[d];
    if (sy >= 0 && sy < gh && sx >= 0 && sx < gw) {
      int src = b * per + sy * gw + sx;
      float cartx = pdx - posl[src * 2];
      float carty = pdy - posl[src * 2 + 1];
      float p0 = cartx * inv2M + 0.5f;
      float p1 = carty * inv2M + 0.5f;
      int k00, k01, k10, k11; float w00, w01, w10, w11;
      corners(p0, p1, k00, k01, k10, k11, w00, w01, w10, w11);
      float xs = xl[src * F + f] * invc;
      acc[k00] += w00 * xs;
      acc[k01] += w01 * xs;
      acc[k10] += w10 * xs;
      acc[k11] += w11 * xs;
    }
  }
  int ldA = 26 * F;
  float* Ar = &Aout[(size_t)dst * ldA];
#pragma unroll
  for (int k = 0; k < 25; k++) Ar[k * F + f] = acc[k];
  Ar[25 * F + f] = xl[dst * F + f];  // root columns
}

// ---------- pack B2 ([W2;root2]) and B3 ([W3;root3]); zero max scalars -----
__global__ __launch_bounds__(256) void pack_kernel(
    const float* __restrict__ W2, const float* __restrict__ root2,
    const float* __restrict__ W3, const float* __restrict__ root3,
    float* __restrict__ B2, float* __restrict__ B3,
    unsigned* __restrict__ maxc2, unsigned* __restrict__ maxc3) {
  int i = blockIdx.x * 256 + threadIdx.x;
  if (i == 0) { *maxc2 = 0u; *maxc3 = 0u; }
  // B2: 25*32*64 = 51200 W2 + 2048 root2 = 53248
  if (i < 53248) B2[i] = (i < 51200) ? W2[i] : root2[i - 51200];
  // B3: 25*64*64 = 102400 W3 + 4096 root3 = 106496
  if (i < 106496) B3[i] = (i < 102400) ? W3[i] : root3[i - 102400];
}

// ---------------------- split-K GEMM (partials) ----------------------------
// P[s][M][N] += A[M, s*chunk : (s+1)*chunk] @ B[same rows, N]
// grid: (N/64, M/64, S). chunk % 16 == 0.
__global__ __launch_bounds__(256) void gemm_splitk_kernel(
    const float* __restrict__ A, const float* __restrict__ B,
    float* __restrict__ P, int M, int N, int K, int chunk) {
  __shared__ float At[16][64];
  __shared__ float Bt[16][64];
  int n0 = blockIdx.x * 64, m0 = blockIdx.y * 64, s = blockIdx.z;
  int kbeg = s * chunk, kend = kbeg + chunk;
  int t = threadIdx.x;
  int tx = t % 16, ty = t / 16;
  int ar = t / 4, ak = (t % 4) * 4;
  int bk = t / 16, bn = (t % 16) * 4;
  float acc[4][4];
#pragma unroll
  for (int i = 0; i < 4; i++)
#pragma unroll
    for (int j = 0; j < 4; j++) acc[i][j] = 0.f;

  for (int k0 = kbeg; k0 < kend; k0 += 16) {
    float4 av = *(const float4*)&A[(size_t)(m0 + ar) * K + k0 + ak];
    float4 bv = *(const float4*)&B[(size_t)(k0 + bk) * N + n0 + bn];
    __syncthreads();
    At[ak + 0][ar] = av.x; At[ak + 1][ar] = av.y;
    At[ak + 2][ar] = av.z; At[ak + 3][ar] = av.w;
    *(float4*)&Bt[bk][bn] = bv;
    __syncthreads();
#pragma unroll
    for (int kk = 0; kk < 16; kk++) {
      float4 a = *(const float4*)&At[kk][ty * 4];
      float4 bq = *(const float4*)&Bt[kk][tx * 4];
      acc[0][0] += a.x * bq.x; acc[0][1] += a.x * bq.y; acc[0][2] += a.x * bq.z; acc[0][3] += a.x * bq.w;
      acc[1][0] += a.y * bq.x; acc[1][1] += a.y * bq.y; acc[1][2] += a.y * bq.z; acc[1][3] += a.y * bq.w;
      acc[2][0] += a.z * bq.x; acc[2][1] += a.z * bq.y; acc[2][2] += a.z * bq.z; acc[2][3] += a.z * bq.w;
      acc[3][0] += a.w * bq.x; acc[3][1] += a.w * bq.y; acc[3][2] += a.w * bq.z; acc[3][3] += a.w * bq.w;
    }
  }
  float* Pq = P + (size_t)s * M * N;
#pragma unroll
  for (int i = 0; i < 4; i++) {
    int m = m0 + ty * 4 + i;
#pragma unroll
    for (int j = 0; j < 4; j++)
      Pq[(size_t)m * N + (n0 + tx * 4 + j)] = acc[i][j];
  }
}

// --------------- reduce split-K partials + bias + ELU ----------------------
// N % 4 == 0; one thread per 4 consecutive output elements.
__global__ __launch_bounds__(256) void reduce_elu_kernel(
    const float* __restrict__ P, const float* __restrict__ bias,
    float* __restrict__ C, int M, int N, int S) {
  int id = blockIdx.x * 256 + threadIdx.x;  // M*N/4 threads exact
  size_t idx4 = (size_t)id * 4;
  int n = (int)(idx4 % N);
  float4 sum = *(const float4*)&P[idx4];
  size_t stride = (size_t)M * N;
  for (int s = 1; s < S; s++) {
    float4 p = *(const float4*)&P[s * stride + idx4];
    sum.x += p.x; sum.y += p.y; sum.z += p.z; sum.w += p.w;
  }
  float4 bv = *(const float4*)&bias[n];
  sum.x = elu_f(sum.x + bv.x); sum.y = elu_f(sum.y + bv.y);
  sum.z = elu_f(sum.z + bv.z); sum.w = elu_f(sum.w + bv.w);
  *(float4*)&C[idx4] = sum;
}

// ------------------------------- GEMM (FC1) --------------------------------
__global__ __launch_bounds__(256) void gemm_kernel(
    const float* __restrict__ A, const float* __restrict__ B,
    const float* __restrict__ bias, float* __restrict__ C,
    int M, int N, int K, int do_elu) {
  __shared__ float At[16][64];
  __shared__ float Bt[16][64];
  int n0 = blockIdx.x * 64, m0 = blockIdx.y * 64;
  int t = threadIdx.x;
  int tx = t % 16, ty = t / 16;
  int ar = t / 4, ak = (t % 4) * 4;
  int bk = t / 16, bn = (t % 16) * 4;
  float acc[4][4];
#pragma unroll
  for (int i = 0; i < 4; i++)
#pragma unroll
    for (int j = 0; j < 4; j++) acc[i][j] = 0.f;

  for (int k0 = 0; k0 < K; k0 += 16) {
    float4 av = *(const float4*)&A[(size_t)(m0 + ar) * K + k0 + ak];
    float4 bv = *(const float4*)&B[(size_t)(k0 + bk) * N + n0 + bn];
    __syncthreads();
    At[ak + 0][ar] = av.x; At[ak + 1][ar] = av.y;
    At[ak + 2][ar] = av.z; At[ak + 3][ar] = av.w;
    *(float4*)&Bt[bk][bn] = bv;
    __syncthreads();
#pragma unroll
    for (int kk = 0; kk < 16; kk++) {
      float4 a = *(const float4*)&At[kk][ty * 4];
      float4 bq = *(const float4*)&Bt[kk][tx * 4];
      acc[0][0] += a.x * bq.x; acc[0][1] += a.x * bq.y; acc[0][2] += a.x * bq.z; acc[0][3] += a.x * bq.w;
      acc[1][0] += a.y * bq.x; acc[1][1] += a.y * bq.y; acc[1][2] += a.y * bq.z; acc[1][3] += a.y * bq.w;
      acc[2][0] += a.z * bq.x; acc[2][1] += a.z * bq.y; acc[2][2] += a.z * bq.z; acc[2][3] += a.z * bq.w;
      acc[3][0] += a.w * bq.x; acc[3][1] += a.w * bq.y; acc[3][2] += a.w * bq.z; acc[3][3] += a.w * bq.w;
    }
  }
#pragma unroll
  for (int i = 0; i < 4; i++) {
    int m = m0 + ty * 4 + i;
#pragma unroll
    for (int j = 0; j < 4; j++) {
      int n = n0 + tx * 4 + j;
      float v = acc[i][j] + bias[n];
      if (do_elu) v = elu_f(v);
      C[(size_t)m * N + n] = v;
    }
  }
}

// -------------------- generic pool (pools 2 & 3) ---------------------------
__global__ __launch_bounds__(256) void poolgen_kernel(
    const float* __restrict__ xl, const float* __restrict__ posl,
    float* __restrict__ xout, float* __restrict__ posout,
    int F, int perin, int gOut, float size) {
  int id = blockIdx.x * 256 + threadIdx.x;
  int g = id % F, s = id / F;
  int per = gOut * gOut;
  int b = s / per, r = s % per;
  float vmax = -3.4e38f;
  float psum = 0.f;
  int cnt = 0;
  for (int j = 0; j < perin; j++) {
    int nc = b * perin + j;
    float px = posl[nc * 2], py = posl[nc * 2 + 1];
    int c2x = (int)floorf(px / size); c2x = c2x < 0 ? 0 : (c2x > gOut - 1 ? gOut - 1 : c2x);
    int c2y = (int)floorf(py / size); c2y = c2y < 0 ? 0 : (c2y > gOut - 1 ? gOut - 1 : c2y);
    if (c2y * gOut + c2x == r) {
      vmax = fmaxf(vmax, xl[nc * F + g]);
      cnt++;
      if (g < 2) psum += posl[nc * 2 + g];
    }
  }
  xout[s * F + g] = vmax;
  if (g < 2 && posout) posout[s * 2 + g] = psum / (float)cnt;
}

// --------------------- FC2 + log_softmax (256 rows) ------------------------
__global__ __launch_bounds__(256) void fc2_lsm_kernel(
    const float* __restrict__ h4, const float* __restrict__ w,
    const float* __restrict__ bias, float* __restrict__ out) {
  int row = threadIdx.x;  // one block of 256
  float l[10];
#pragma unroll
  for (int j = 0; j < 10; j++) l[j] = bias[j];
  for (int k = 0; k < 128; k++) {
    float hv = h4[row * 128 + k];
#pragma unroll
    for (int j = 0; j < 10; j++) l[j] += hv * w[k * 10 + j];
  }
  float m = l[0];
#pragma unroll
  for (int j = 1; j < 10; j++) m = fmaxf(m, l[j]);
  float ssum = 0.f;
#pragma unroll
  for (int j = 0; j < 10; j++) ssum += expf(l[j] - m);
  float lse = logf(ssum);
#pragma unroll
  for (int j = 0; j < 10; j++) out[row * 10 + j] = l[j] - m - lse;
}

// ---------------------------------------------------------------------------
extern "C" void kernel_launch(void* const* d_in, const int* in_sizes, int n_in,
                              void* d_out, int out_size, void* d_ws, size_t ws_size,
                              hipStream_t stream) {
  const float* x      = (const float*)d_in[0];
  const float* pos    = (const float*)d_in[1];
  const float* pseudo = (const float*)d_in[2];
  const float* W1     = (const float*)d_in[3];
  const float* root1  = (const float*)d_in[4];
  const float* b1     = (const float*)d_in[5];
  const float* W2     = (const float*)d_in[6];
  const float* root2  = (const float*)d_in[7];
  const float* b2     = (const float*)d_in[8];
  const float* W3     = (const float*)d_in[9];
  const float* root3  = (const float*)d_in[10];
  const float* b3     = (const float*)d_in[11];
  const float* fc1w   = (const float*)d_in[12];
  const float* fc1b   = (const float*)d_in[13];
  const float* fc2w   = (const float*)d_in[14];
  const float* fc2b   = (const float*)d_in[15];
  float* out = (float*)d_out;

  // workspace layout (floats)
  float* ws = (float*)d_ws;
  size_t o = 0;
  float* w_out1 = ws + o; o += (size_t)200704 * 32;   // 6.42M; reused as split-K partials
  float* w_h1p  = ws + o; o += (size_t)9216 * 32;
  float* w_pos1 = ws + o; o += (size_t)9216 * 2;
  float* w_A    = ws + o; o += (size_t)9216 * 832;    // A2 (9216x832) / A3 (4096x1664)
  float* w_B2   = ws + o; o += (size_t)832 * 64;
  float* w_B3   = ws + o; o += (size_t)1664 * 64;
  float* w_h2   = ws + o; o += (size_t)9216 * 64;
  float* w_pos2 = ws + o; o += (size_t)4096 * 2;
  float* w_h2p  = ws + o; o += (size_t)4096 * 64;
  float* w_h3   = ws + o; o += (size_t)4096 * 64;
  float* w_h3p  = ws + o; o += (size_t)1024 * 64;
  float* w_h4   = ws + o; o += (size_t)256 * 128;
  unsigned* w_maxc2 = (unsigned*)(ws + o); o += 4;
  unsigned* w_maxc3 = (unsigned*)(ws + o); o += 4;
  float* w_P = w_out1;  // split-K partials: max 8*4096*64 = 2.1M floats < 6.42M

  // pack B2/B3, zero atomicMax scalars (one dispatch)
  pack_kernel<<<416, 256, 0, stream>>>(W2, root2, W3, root3, w_B2, w_B3,
                                       w_maxc2, w_maxc3);
  // L1 + P1
  spline1_kernel<<<784, 256, 0, stream>>>(x, pseudo, W1, root1, b1, w_out1);
  pool1_kernel<<<1152, 256, 0, stream>>>(w_out1, pos, w_h1p, w_pos1);
  // L2: 9216 x 832 x 64, split-K S=4 (chunk 208) -> 576 blocks
  maxcart_kernel<<<36, 256, 0, stream>>>(w_pos1, w_maxc2, 6, 6, 9216);
  ubuild_kernel<<<2304, 128, 0, stream>>>(w_h1p, w_pos1, w_maxc2, w_A, 32, 6, 6);
  gemm_splitk_kernel<<<dim3(1, 144, 4), 256, 0, stream>>>(w_A, w_B2, w_P, 9216, 64, 832, 208);
  reduce_elu_kernel<<<576, 256, 0, stream>>>(w_P, b2, w_h2, 9216, 64, 4);
  // P2
  poolgen_kernel<<<1024, 256, 0, stream>>>(w_h2, w_pos1, w_h2p, w_pos2, 64, 36, 4, 7.0f);
  // L3: 4096 x 1664 x 64, split-K S=8 (chunk 208) -> 512 blocks
  maxcart_kernel<<<16, 256, 0, stream>>>(w_pos2, w_maxc3, 4, 4, 4096);
  ubuild_kernel<<<2048, 128, 0, stream>>>(w_h2p, w_pos2, w_maxc3, w_A, 64, 4, 4);
  gemm_splitk_kernel<<<dim3(1, 64, 8), 256, 0, stream>>>(w_A, w_B3, w_P, 4096, 64, 1664, 208);
  reduce_elu_kernel<<<256, 256, 0, stream>>>(w_P, b3, w_h3, 4096, 64, 8);
  // P3
  poolgen_kernel<<<256, 256, 0, stream>>>(w_h3, w_pos2, w_h3p, nullptr, 64, 16, 2, 14.0f);
  // FC1 + FC2/log_softmax
  gemm_kernel<<<dim3(2, 4), 256, 0, stream>>>(w_h3p, fc1w, fc1b, w_h4, 256, 128, 256, 1);
  fc2_lsm_kernel<<<1, 256, 0, stream>>>(w_h4, fc2w, fc2b, out);
}